// Round 6
// baseline (2971.086 us; speedup 1.0000x reference)
//
#include <hip/hip_runtime.h>
#include <hip/hip_fp16.h>

// LSTMPredictor: B=32, T=512, H=128, L=5, IN=1, OUT=16, future=18 -> 3 autoregressive iters.
// ONE 514-step scan with carried (h,c); FC head at t=511,512,513; feedback via fcout/fcflag.
// 160 persistent WGs = 32 batch x 5 layers; 4-step chunked sc1 h-transport (R4 protocol).
//
// R6: fit under the 128-VGPR cap BY CONSTRUCTION (R4/R5 evidence: allocator pins 128,
// ~220-reg design -> weights scratch-streamed ~390KB/WG-step -> 12.7k cyc steps).
// 1024 threads/WG: each thread = 1 gate-row x 64 k -> whh 32xf2 (64 VGPR) + wih 32xhalf2
// (32 VGPR) + ~25 working = ~120 regs. Bias/wx in LDS. kg-pair shfl reduce + LDS gsum
// gather -> 128 update threads. One WG/CU (16 waves x 128 VGPR = full file).

typedef float f2 __attribute__((ext_vector_type(2)));

#define RING 16
#define TAIL 500                      // chunk-aligned switch to per-step mode
#define GUARD (1<<16)

#define FLAGL_OFF   0                 // int flagL[32][5], stride 64 ints
#define FCFLAG_OFF  (64*1024)         // int fcflag[32], stride 64 ints
#define FCOUT_OFF   (128*1024)        // float fcout[32][2]
#define RING_OFF    (256*1024)        // float ring[32][4][RING][128]  (1 MB)
#define WHHP_OFF    (2*1024*1024)     // f2 WhhP[5][64][512]           (1.25 MB)
#define WIHPK_OFF   (4*1024*1024)     // __half2 WihPk[4][64][512]     (0.5 MB)

#define AGENT __HIP_MEMORY_SCOPE_AGENT
#define LD(p)    __hip_atomic_load((p),  __ATOMIC_RELAXED, AGENT)
#define ST(p,v)  __hip_atomic_store((p), (v), __ATOMIC_RELAXED, AGENT)

__device__ __forceinline__ void bar_lgkm() {   // barrier w/o vmcnt drain (LDS hazards only)
    asm volatile("s_waitcnt lgkmcnt(0)\n\ts_barrier" ::: "memory");
}
__device__ __forceinline__ void drain_vm() {   // drain own wave's global ops
    asm volatile("s_waitcnt vmcnt(0)" ::: "memory");
}

__device__ __forceinline__ float sigm(float x)   { return 1.f / (1.f + __expf(-x)); }
__device__ __forceinline__ float tanh_f(float x) { return 2.f / (1.f + __expf(-2.f * x)) - 1.f; }

// ---------------- init: zero flags, pair-pack W_hh (fp32) and W_ih_rest (f16) ----------
__global__ void lstm_init(const float* __restrict__ WihR, const float* __restrict__ Whh,
                          char* __restrict__ ws)
{
    int idx = blockIdx.x * blockDim.x + threadIdx.x;
    int stride = gridDim.x * blockDim.x;

    int* wsi = (int*)ws;                       // zero [0, 256KB): flags + fcout
    for (int i = idx; i < 65536; i += stride) wsi[i] = 0;

    f2* WP2 = (f2*)(ws + WHHP_OFF);            // WhhP[(l*64+km)*512+row] = Whh[l][row][2km..+1]
    for (int i = idx; i < 5*64*512; i += stride) {
        int row = i & 511, km = (i >> 9) & 63, l = i >> 15;
        const float* s = &Whh[(l*512 + row)*128 + 2*km];
        f2 v; v.x = s[0]; v.y = s[1];
        WP2[i] = v;
    }

    __half2* WH = (__half2*)(ws + WIHPK_OFF);  // WihPk[(li*64+km)*512+row]
    for (int i = idx; i < 4*64*512; i += stride) {
        int row = i & 511, km = (i >> 9) & 63, li = i >> 15;
        const float* s = &WihR[(li*512 + row)*128 + 2*km];
        WH[i] = __floats2half2_rn(s[0], s[1]);
    }
}

// ---------------- main persistent pipeline kernel ----------------
__global__ void __launch_bounds__(1024)
lstm_main(const float* __restrict__ x_in, const float* __restrict__ Wih0,
          const float* __restrict__ bih,  const float* __restrict__ bhh,
          const float* __restrict__ W1,   const float* __restrict__ b1,
          const float* __restrict__ W2,   const float* __restrict__ b2,
          float* __restrict__ out, char* __restrict__ ws)
{
    __shared__ __align__(16) float hown[128];   // this layer's h(t-1)
    __shared__ __align__(16) float hc_in[512];  // incoming h chunk (l==0: holds x[b])
    __shared__ __align__(16) float hc_out[512]; // outgoing h chunk
    __shared__ __align__(16) float gsum[512];   // gate sums (r*4+j)
    __shared__ float4 bias4[128];               // per-row (i,f,g,o) bias
    __shared__ float4 wx4[128];                 // layer-0 Wih0 per-row (i,f,g,o)
    __shared__ float zbs[128];                  // FC: relu(h)
    __shared__ float z2s[128];                  // FC: relu(z@W1+b1)

    const int tid = threadIdx.x;
    const int kg = tid & 1;            // k-half 0..1 (adjacent lanes -> shfl reduce)
    const int j  = (tid >> 1) & 3;     // gate 0..3 (i,f,g,o)
    const int r  = tid >> 3;           // hidden row 0..127
    const int b = blockIdx.x / 5;
    const int l = blockIdx.x % 5;
    const bool isProd = (l < 4);
    const bool isCons = (l > 0);

    int*   flagL  = (int*)(ws + FLAGL_OFF);
    int*   fcflag = (int*)(ws + FCFLAG_OFF) + b*64;
    float* fcout  = (float*)(ws + FCOUT_OFF) + b*2;
    float* ringAll= (float*)(ws + RING_OFF);
    const f2*      WP2 = (const f2*)(ws + WHHP_OFF);
    const __half2* WH  = (const __half2*)(ws + WIHPK_OFF);

    int* upflag = flagL + (b*5 + (l > 0 ? l-1 : 0))*64;
    int* dnflag = flagL + (b*5 + (l < 4 ? l+1 : 4))*64;
    int* myflag = flagL + (b*5 + l)*64;
    float* upRing = ringAll + (b*4 + (l > 0 ? l-1 : 0))*RING*128;
    float* myRing = ringAll + (b*4 + (l < 4 ? l   : 0))*RING*128;

    // ---- register-resident weights: 1 gate-row x 64 k per thread ----
    // whh2[m] = {W_hh[l][j*128+r][kg*64+2m], [+1]}   (32 f2 = 64 VGPRs, fp32-exact)
    f2 whh2[32];
#pragma unroll
    for (int m = 0; m < 32; ++m)
        whh2[m] = WP2[(l*64 + kg*32 + m)*512 + j*128 + r];

    __half2 wih[32];                   // f16 pairs (32 VGPRs), layers 1..4 only
    if (isCons) {
#pragma unroll
        for (int m = 0; m < 32; ++m)
            wih[m] = WH[((l-1)*64 + kg*32 + m)*512 + j*128 + r];
    }

    if (tid < 128) {
        bias4[tid] = make_float4(bih[l*512 +       tid] + bhh[l*512 +       tid],
                                 bih[l*512 + 128 + tid] + bhh[l*512 + 128 + tid],
                                 bih[l*512 + 256 + tid] + bhh[l*512 + 256 + tid],
                                 bih[l*512 + 384 + tid] + bhh[l*512 + 384 + tid]);
        if (l == 0)
            wx4[tid] = make_float4(Wih0[tid], Wih0[128+tid], Wih0[256+tid], Wih0[384+tid]);
        hown[tid] = 0.f;               // h(-1) = 0
    }
    if (l == 0 && tid < 512) hc_in[tid] = x_in[b*512 + tid];   // x preload (l0 never uses hc_in)
    __syncthreads();

    float c = 0.f;                     // cell state (tid<128 lanes)
    int lastup = 0, lastdn = 0;

    for (int t = 0; t < 514; ++t) {
        const int sub = t & 3;

        // ================= transport: chunk start / tail per-step =================
        if (t < TAIL) {
            if (sub == 0) {
                float hv = 0.f;
                if (isCons) {
                    int guard = 0;                      // need producer chunk [t..t+3] done
                    while (lastup < t+4) {
                        if (++guard > GUARD) break;     // fail loud, never hang
                        lastup = LD(upflag);
                    }
                    if (tid < 512) hv = LD(&upRing[(t & (RING-1))*128 + tid]);  // 2KB
                }
                drain_vm();            // drains own chunk load AND last chunk's ring store
                if (isCons && tid < 512) hc_in[tid] = hv;
                bar_lgkm();            // hc_in visible; all waves' stores drained
                if (t > 0 && tid == 0) ST(myflag, t);   // publish previous chunk
            }
        } else {
            // tail: per-step transport (feedback region)
            if (isCons) {
                int guard = 0;
                while (lastup < t+1) {
                    if (++guard > GUARD) break;
                    lastup = LD(upflag);
                }
                float hv = 0.f;
                if (tid < 128) hv = LD(&upRing[(t & (RING-1))*128 + tid]);
                drain_vm();
                if (tid < 128) hc_in[sub*128 + tid] = hv;
            } else {
                drain_vm();
            }
            bar_lgkm();
        }

        // ================= matvec: recurrent (fp32 pk-fma) + input (f16) =========
        f2 a2; a2.x = 0.f; a2.y = 0.f;
        {
            const f2* h2 = (const f2*)hown + kg*32;
#pragma unroll
            for (int m = 0; m < 32; ++m)
                a2 = __builtin_elementwise_fma(whh2[m], h2[m], a2);
        }
        float a = a2.x + a2.y;
        if (isCons) {
            const f2* hi2 = (const f2*)(hc_in + sub*128) + kg*32;
#pragma unroll
            for (int m = 0; m < 32; ++m) {
                __half2 w = wih[m];
                f2 hh = hi2[m];
                a = fmaf(__low2float(w),  hh.x, a);
                a = fmaf(__high2float(w), hh.y, a);
            }
        }
        a += __shfl_xor(a, 1, 64);     // combine kg pair
        if (kg == 0) gsum[tid >> 1] = a;   // gsum[r*4+j], conflict-free
        bar_lgkm();

        // ================= cell update: 128 threads (2 waves) ====================
        if (tid < 128) {
            float xt = 0.f;
            if (l == 0) {
                if (t < 512) xt = hc_in[t];     // preloaded x
                else {
                    int need = t - 511, guard = 0;
                    int f = LD(fcflag);
                    while (f < need) {
                        if (++guard > GUARD) break;
                        f = LD(fcflag);
                    }
                    xt = LD(&fcout[t-512]);
                }
            }
            float4 gv = *(const float4*)&gsum[tid*4];
            float4 bv = bias4[tid];
            float gi = bv.x + gv.x, gf = bv.y + gv.y;
            float gg = bv.z + gv.z, go = bv.w + gv.w;
            if (l == 0) {
                float4 wv = wx4[tid];
                gi = fmaf(wv.x, xt, gi); gf = fmaf(wv.y, xt, gf);
                gg = fmaf(wv.z, xt, gg); go = fmaf(wv.w, xt, go);
            }
            float si = sigm(gi), sf = sigm(gf), gt = tanh_f(gg), so = sigm(go);
            c = fmaf(sf, c, si*gt);
            float h = so * tanh_f(c);
            hown[tid] = h;
            if (isProd) {
                if (t < TAIL) hc_out[sub*128 + tid] = h;
                else          ST(&myRing[(t & (RING-1))*128 + tid], h);
            }
        }
        bar_lgkm();    // hown (+hc_out) visible

        // ================= transport: chunk end / tail publish =================
        if (t < TAIL) {
            if (sub == 3 && isProd) {
                // backpressure: consumer must have loaded chunk t-15 before overwrite
                if (t >= RING && lastdn < t-15) {
                    int guard = 0;
                    while (lastdn < t-15) {
                        if (++guard > GUARD) break;
                        lastdn = LD(dnflag);
                    }
                }
                if (tid < 512)
                    ST(&myRing[((t-3) & (RING-1))*128 + tid], hc_out[tid]);  // 2KB, no drain
            }
        } else {
            drain_vm();                 // tail: drain h store
            bar_lgkm();
            if (tid == 0) ST(myflag, t+1);
        }

        // ================= FC head (l==4, t>=511; 3x total) =================
        if (l == 4 && t >= 511) {
            const int iter = t - 511;
            if (tid < 128) zbs[tid] = fmaxf(hown[tid], 0.f);
            bar_lgkm();
            if (tid < 128) {
                float acc = b1[tid];
#pragma unroll 8
                for (int k = 0; k < 128; ++k)
                    acc = fmaf(zbs[k], W1[k*128 + tid], acc);   // W1 from L2 (3x only)
                z2s[tid] = fmaxf(acc, 0.f);
            }
            bar_lgkm();
            if (tid < 16) {
                float o = b2[tid];
#pragma unroll 8
                for (int m = 0; m < 128; ++m)
                    o = fmaf(z2s[m], W2[m*16 + tid], o);
                if (iter == 2) {
                    out[b*18 + 2 + tid] = o;                // out2 full 16
                } else if (tid == 15) {
                    out[b*18 + iter] = o;                   // out_i[:, 15]
                    ST(&fcout[iter], o);
                    drain_vm();                             // fcout visible first
                    ST(fcflag, iter+1);
                }
            }
            bar_lgkm();
        }
    }
}

extern "C" void kernel_launch(void* const* d_in, const int* in_sizes, int n_in,
                              void* d_out, int out_size, void* d_ws, size_t ws_size,
                              hipStream_t stream) {
    (void)in_sizes; (void)n_in; (void)out_size; (void)ws_size;  // needs ~4.5 MB of ws
    const float* x    = (const float*)d_in[0];
    // d_in[1] = future (18, hardcoded)
    const float* Wih0 = (const float*)d_in[2];
    const float* WihR = (const float*)d_in[3];
    const float* Whh  = (const float*)d_in[4];
    const float* bihp = (const float*)d_in[5];
    const float* bhhp = (const float*)d_in[6];
    const float* W1   = (const float*)d_in[7];
    const float* b1   = (const float*)d_in[8];
    const float* W2   = (const float*)d_in[9];
    const float* b2   = (const float*)d_in[10];
    char* ws = (char*)d_ws;

    lstm_init<<<256, 256, 0, stream>>>(WihR, Whh, ws);
    lstm_main<<<160, 1024, 0, stream>>>(x, Wih0, bihp, bhhp, W1, b1, W2, b2,
                                        (float*)d_out, ws);
}

// Round 7
// 2517.088 us; speedup vs baseline: 1.1804x; 1.1804x over previous
//
#include <hip/hip_runtime.h>
#include <hip/hip_fp16.h>

// LSTMPredictor: B=32, T=512, H=128, L=5, IN=1, OUT=16, future=18 -> 3 autoregressive iters.
// ONE 514-step scan with carried (h,c); FC head at t=511,512,513; feedback via fcout/fcflag.
// 160 persistent WGs = 32 batch x 5 layers; 4-step chunked sc1 h-transport.
//
// R7: (a) register budget via amdgpu_flat_work_group_size(1024,1024)+amdgpu_waves_per_eu(4,4)
//     (R4-R6 evidence: default budget = 65536/threads = 2 WG/CU -> weights scratch-streamed);
//     (b) even/odd k-interleave (thread kg owns f2 idx 2m+kg) -> dual-address h-broadcast
//     hits disjoint banks -> kills the 1.5e8 LDS conflicts;
//     (c) f16 h for the ih matvec + f16 ring (ih weights already f16 -> in-noise) -> LDS
//     return-bus and transport bytes shrink.

typedef float f2 __attribute__((ext_vector_type(2)));

#define RING 16
#define TAIL 500                      // chunk-aligned switch to per-step mode
#define GUARD (1<<16)

#define FLAGL_OFF   0                 // int flagL[32][5], stride 64 ints
#define FCFLAG_OFF  (64*1024)         // int fcflag[32], stride 64 ints
#define FCOUT_OFF   (128*1024)        // float fcout[32][2]
#define RING_OFF    (256*1024)        // uint ring[32][4][RING][64]  (half2 payload, 512 KB)
#define WHHP_OFF    (2*1024*1024)     // f2 WhhP[5][64][512]           (1.25 MB)
#define WIHPK_OFF   (4*1024*1024)     // __half2 WihPk[4][64][512]     (0.5 MB)

#define AGENT __HIP_MEMORY_SCOPE_AGENT
#define LD(p)    __hip_atomic_load((p),  __ATOMIC_RELAXED, AGENT)
#define ST(p,v)  __hip_atomic_store((p), (v), __ATOMIC_RELAXED, AGENT)

__device__ __forceinline__ void bar_lgkm() {   // barrier w/o vmcnt drain (LDS hazards only)
    asm volatile("s_waitcnt lgkmcnt(0)\n\ts_barrier" ::: "memory");
}
__device__ __forceinline__ void drain_vm() {   // drain own wave's global ops
    asm volatile("s_waitcnt vmcnt(0)" ::: "memory");
}

__device__ __forceinline__ float sigm(float x)   { return 1.f / (1.f + __expf(-x)); }
__device__ __forceinline__ float tanh_f(float x) { return 2.f / (1.f + __expf(-2.f * x)) - 1.f; }

// ---------------- init: zero flags, pair-pack W_hh (fp32) and W_ih_rest (f16) ----------
__global__ void lstm_init(const float* __restrict__ WihR, const float* __restrict__ Whh,
                          char* __restrict__ ws)
{
    int idx = blockIdx.x * blockDim.x + threadIdx.x;
    int stride = gridDim.x * blockDim.x;

    int* wsi = (int*)ws;                       // zero [0, 256KB): flags + fcout
    for (int i = idx; i < 65536; i += stride) wsi[i] = 0;

    f2* WP2 = (f2*)(ws + WHHP_OFF);            // WhhP[(l*64+km)*512+row] = Whh[l][row][2km..+1]
    for (int i = idx; i < 5*64*512; i += stride) {
        int row = i & 511, km = (i >> 9) & 63, l = i >> 15;
        const float* s = &Whh[(l*512 + row)*128 + 2*km];
        f2 v; v.x = s[0]; v.y = s[1];
        WP2[i] = v;
    }

    __half2* WH = (__half2*)(ws + WIHPK_OFF);  // WihPk[(li*64+km)*512+row]
    for (int i = idx; i < 4*64*512; i += stride) {
        int row = i & 511, km = (i >> 9) & 63, li = i >> 15;
        const float* s = &WihR[(li*512 + row)*128 + 2*km];
        WH[i] = __floats2half2_rn(s[0], s[1]);
    }
}

// ---------------- main persistent pipeline kernel ----------------
__global__ void
__attribute__((amdgpu_flat_work_group_size(1024, 1024), amdgpu_waves_per_eu(4, 4)))
lstm_main(const float* __restrict__ x_in, const float* __restrict__ Wih0,
          const float* __restrict__ bih,  const float* __restrict__ bhh,
          const float* __restrict__ W1,   const float* __restrict__ b1,
          const float* __restrict__ W2,   const float* __restrict__ b2,
          float* __restrict__ out, char* __restrict__ ws)
{
    __shared__ __align__(16) float hown[128];          // this layer's h(t-1), fp32
    __shared__ __align__(16) unsigned int hinU[256];   // incoming h chunk, 4 slots x 64 half2
    __shared__ __align__(16) unsigned int houtU[256];  // outgoing h chunk (half2)
    __shared__ __align__(16) float gsum[512];          // gate sums (r*4+j)
    __shared__ float4 bias4[128];                      // per-row (i,f,g,o) bias
    __shared__ float4 wx4[128];                        // layer-0 Wih0 per-row
    __shared__ float xbuf[512];                        // layer-0 input sequence
    __shared__ float zbs[128];                         // FC: relu(h)
    __shared__ float z2s[128];                         // FC: relu(z@W1+b1)

    const int tid = threadIdx.x;
    const int kg = tid & 1;            // k-parity (even/odd f2 indices -> disjoint banks)
    const int j  = (tid >> 1) & 3;     // gate 0..3 (i,f,g,o)
    const int r  = tid >> 3;           // hidden row 0..127
    const int b = blockIdx.x / 5;
    const int l = blockIdx.x % 5;
    const bool isProd = (l < 4);
    const bool isCons = (l > 0);

    int*   flagL  = (int*)(ws + FLAGL_OFF);
    int*   fcflag = (int*)(ws + FCFLAG_OFF) + b*64;
    float* fcout  = (float*)(ws + FCOUT_OFF) + b*2;
    unsigned int* ringU = (unsigned int*)(ws + RING_OFF);
    const f2*      WP2 = (const f2*)(ws + WHHP_OFF);
    const __half2* WH  = (const __half2*)(ws + WIHPK_OFF);

    int* upflag = flagL + (b*5 + (l > 0 ? l-1 : 0))*64;
    int* dnflag = flagL + (b*5 + (l < 4 ? l+1 : 4))*64;
    int* myflag = flagL + (b*5 + l)*64;
    unsigned int* upRingU = ringU + (b*4 + (l > 0 ? l-1 : 0))*RING*64;
    unsigned int* myRingU = ringU + (b*4 + (l < 4 ? l   : 0))*RING*64;

    // ---- register-resident weights: 1 gate-row, even/odd k-pairs ----
    // whh2[m] = {W_hh[l][j*128+r][2*(2m+kg)], [+1]}   (32 f2 = 64 VGPRs, fp32-exact)
    f2 whh2[32];
#pragma unroll
    for (int m = 0; m < 32; ++m)
        whh2[m] = WP2[(l*64 + 2*m + kg)*512 + j*128 + r];

    __half2 wih[32];                   // f16 pairs (32 VGPRs), layers 1..4 only
    if (isCons) {
#pragma unroll
        for (int m = 0; m < 32; ++m)
            wih[m] = WH[((l-1)*64 + 2*m + kg)*512 + j*128 + r];
    }

    if (tid < 128) {
        bias4[tid] = make_float4(bih[l*512 +       tid] + bhh[l*512 +       tid],
                                 bih[l*512 + 128 + tid] + bhh[l*512 + 128 + tid],
                                 bih[l*512 + 256 + tid] + bhh[l*512 + 256 + tid],
                                 bih[l*512 + 384 + tid] + bhh[l*512 + 384 + tid]);
        if (l == 0)
            wx4[tid] = make_float4(Wih0[tid], Wih0[128+tid], Wih0[256+tid], Wih0[384+tid]);
        hown[tid] = 0.f;               // h(-1) = 0
    }
    if (l == 0 && tid < 512) xbuf[tid] = x_in[b*512 + tid];   // preload input sequence
    __syncthreads();

    float c = 0.f;                     // cell state (tid<128 lanes)
    int lastup = 0, lastdn = 0;

    for (int t = 0; t < 514; ++t) {
        const int sub = t & 3;

        // ================= transport: chunk start / tail per-step =================
        if (t < TAIL) {
            if (sub == 0) {
                unsigned int hv = 0;
                if (isCons) {
                    int guard = 0;                      // need producer chunk [t..t+3] done
                    while (lastup < t+4) {
                        if (++guard > GUARD) break;     // fail loud, never hang
                        lastup = LD(upflag);
                    }
                    if (tid < 256) hv = LD(&upRingU[(t & (RING-1))*64 + tid]);  // 1KB chunk
                }
                drain_vm();            // every wave drains own loads AND last chunk-store
                if (isCons && tid < 256) hinU[tid] = hv;
                bar_lgkm();            // hinU visible; all waves' stores drained
                if (t > 0 && tid == 0) ST(myflag, t);   // publish previous chunk
            }
        } else {
            // tail: per-step transport (feedback region)
            if (isCons) {
                int guard = 0;
                while (lastup < t+1) {
                    if (++guard > GUARD) break;
                    lastup = LD(upflag);
                }
                unsigned int hv = 0;
                if (tid < 64) hv = LD(&upRingU[(t & (RING-1))*64 + tid]);
                drain_vm();
                if (tid < 64) hinU[sub*64 + tid] = hv;
            } else {
                drain_vm();
            }
            bar_lgkm();
            // tail entry: publish completion of the final chunk (496..499)
            if (t == TAIL && tid == 0) ST(myflag, TAIL);
        }

        // ================= matvec: recurrent (fp32 pk-fma) + input (f16) =========
        f2 a2; a2.x = 0.f; a2.y = 0.f;
        {
            const f2* h2 = (const f2*)hown;
#pragma unroll
            for (int m = 0; m < 32; ++m)
                a2 = __builtin_elementwise_fma(whh2[m], h2[2*m + kg], a2);
        }
        float a = a2.x + a2.y;
        if (isCons) {
            const __half2* hi2 = ((const __half2*)hinU) + sub*64;
#pragma unroll
            for (int m = 0; m < 32; ++m) {
                __half2 w = wih[m];
                __half2 hh = hi2[2*m + kg];
                a = fmaf(__low2float(w),  __low2float(hh),  a);
                a = fmaf(__high2float(w), __high2float(hh), a);
            }
        }
        a += __shfl_xor(a, 1, 64);     // combine kg pair
        if (kg == 0) gsum[tid >> 1] = a;   // gsum[r*4+j], conflict-free
        bar_lgkm();

        // ================= cell update: 128 threads (2 waves) ====================
        if (tid < 128) {
            float xt = 0.f;
            if (l == 0) {
                if (t < 512) xt = xbuf[t];      // preloaded x (LDS broadcast)
                else {
                    int need = t - 511, guard = 0;
                    int f = LD(fcflag);
                    while (f < need) {
                        if (++guard > GUARD) break;
                        f = LD(fcflag);
                    }
                    xt = LD(&fcout[t-512]);
                }
            }
            float4 gv = *(const float4*)&gsum[tid*4];
            float4 bv = bias4[tid];
            float gi = bv.x + gv.x, gf = bv.y + gv.y;
            float gg = bv.z + gv.z, go = bv.w + gv.w;
            if (l == 0) {
                float4 wv = wx4[tid];
                gi = fmaf(wv.x, xt, gi); gf = fmaf(wv.y, xt, gf);
                gg = fmaf(wv.z, xt, gg); go = fmaf(wv.w, xt, go);
            }
            float si = sigm(gi), sf = sigm(gf), gt = tanh_f(gg), so = sigm(go);
            c = fmaf(sf, c, si*gt);
            float h = so * tanh_f(c);
            hown[tid] = h;
            if (isProd)
                ((__half*)houtU)[sub*128 + tid] = __float2half(h);
        }
        bar_lgkm();    // hown + houtU visible

        // ================= transport: chunk end / tail publish =================
        if (t < TAIL) {
            if (sub == 3 && isProd) {
                // backpressure: consumer must have loaded chunk t-15 before overwrite
                if (t >= RING && lastdn < t-15) {
                    int guard = 0;
                    while (lastdn < t-15) {
                        if (++guard > GUARD) break;
                        lastdn = LD(dnflag);
                    }
                }
                if (tid < 256)
                    ST(&myRingU[((t-3) & (RING-1))*64 + tid], houtU[tid]);  // 1KB, no drain
            }
        } else {
            if (isProd && tid < 64)
                ST(&myRingU[(t & (RING-1))*64 + tid], houtU[sub*64 + tid]);
            drain_vm();                 // tail: drain h store
            bar_lgkm();
            if (tid == 0) ST(myflag, t+1);
        }

        // ================= FC head (l==4, t>=511; 3x total) =================
        if (l == 4 && t >= 511) {
            const int iter = t - 511;
            if (tid < 128) zbs[tid] = fmaxf(hown[tid], 0.f);
            bar_lgkm();
            if (tid < 128) {
                float acc = b1[tid];
#pragma unroll 8
                for (int k = 0; k < 128; ++k)
                    acc = fmaf(zbs[k], W1[k*128 + tid], acc);   // W1 from L2 (3x only)
                z2s[tid] = fmaxf(acc, 0.f);
            }
            bar_lgkm();
            if (tid < 16) {
                float o = b2[tid];
#pragma unroll 8
                for (int m = 0; m < 128; ++m)
                    o = fmaf(z2s[m], W2[m*16 + tid], o);
                if (iter == 2) {
                    out[b*18 + 2 + tid] = o;                // out2 full 16
                } else if (tid == 15) {
                    out[b*18 + iter] = o;                   // out_i[:, 15]
                    ST(&fcout[iter], o);
                    drain_vm();                             // fcout visible first
                    ST(fcflag, iter+1);
                }
            }
            bar_lgkm();
        }
    }
}

extern "C" void kernel_launch(void* const* d_in, const int* in_sizes, int n_in,
                              void* d_out, int out_size, void* d_ws, size_t ws_size,
                              hipStream_t stream) {
    (void)in_sizes; (void)n_in; (void)out_size; (void)ws_size;  // needs ~4.5 MB of ws
    const float* x    = (const float*)d_in[0];
    // d_in[1] = future (18, hardcoded)
    const float* Wih0 = (const float*)d_in[2];
    const float* WihR = (const float*)d_in[3];
    const float* Whh  = (const float*)d_in[4];
    const float* bihp = (const float*)d_in[5];
    const float* bhhp = (const float*)d_in[6];
    const float* W1   = (const float*)d_in[7];
    const float* b1   = (const float*)d_in[8];
    const float* W2   = (const float*)d_in[9];
    const float* b2   = (const float*)d_in[10];
    char* ws = (char*)d_ws;

    lstm_init<<<256, 256, 0, stream>>>(WihR, Whh, ws);
    lstm_main<<<160, 1024, 0, stream>>>(x, Wih0, bihp, bhhp, W1, b1, W2, b2,
                                        (float*)d_out, ws);
}